// Round 3
// baseline (1508.092 us; speedup 1.0000x reference)
//
#include <hip/hip_runtime.h>
#include <math.h>

// StatefulRosenberg: segmented cumsum (16 rows x 1,048,576) + Rosenberg pulse.
// R2->R3: fused single-pass scan via decoupled lookback with per-row ticket
// ordering (ticket order == block start order => lookback is deadlock-free
// without any dispatch-order assumption). f0 read once from HBM.
// fp64 phase accumulation kept (np-ref serial f32 cumsum noise ~3e-4 >> ours).

constexpr int BATCH   = 16;
constexpr int T       = 1048576;
constexpr int THREADS = 256;
constexpr int VPT     = 16;               // elements per thread
constexpr int CHUNK   = THREADS * VPT;    // 4096
constexpr int NCHUNK  = T / CHUNK;        // 256
constexpr int NBLK    = BATCH * NCHUNK;   // 4096

#define INV_SR (1.0f / 48000.0f)

// d_ws layout: agg[NBLK] (32KB) | incl[NBLK] (32KB) | flag[NBLK]+tickets[16] ints
__global__ __launch_bounds__(THREADS) void k_fused(
    const float* __restrict__ f0, const float* __restrict__ oq,
    const float* __restrict__ phase_state,
    double* __restrict__ agg, double* __restrict__ incl,
    int* __restrict__ flag, int* __restrict__ tickets,
    float* __restrict__ wav, float* __restrict__ next_state)
{
    const int row  = blockIdx.y;
    const int lane = threadIdx.x & 63, wid = threadIdx.x >> 6;

    __shared__ int    s_chunk;
    __shared__ double s_excl;
    __shared__ double ws[THREADS / 64];

    if (threadIdx.x == 0) {
        int t = __hip_atomic_fetch_add(&tickets[row], 1,
                                       __ATOMIC_RELAXED, __HIP_MEMORY_SCOPE_AGENT);
        s_chunk = t & (NCHUNK - 1);   // mask: stays in-range even on rocprof replay
    }
    __syncthreads();
    const int chunk = s_chunk;
    const int vid   = row * NCHUNK + chunk;
    const size_t base_idx = (size_t)row * T + (size_t)chunk * CHUNK
                          + (size_t)threadIdx.x * VPT;

    // ---- load f0, f32 steps + thread fp64 sum
    float st[VPT];
    double tsum = 0.0;
    {
        const float4* fb = (const float4*)(f0 + base_idx);
#pragma unroll
        for (int j = 0; j < VPT / 4; ++j) {
            float4 v = fb[j];
            st[4 * j + 0] = v.x * INV_SR;
            st[4 * j + 1] = v.y * INV_SR;
            st[4 * j + 2] = v.z * INV_SR;
            st[4 * j + 3] = v.w * INV_SR;
        }
#pragma unroll
        for (int i = 0; i < VPT; ++i) tsum += (double)st[i];
    }

    // ---- block scan of per-thread sums (wave shfl scan + cross-wave totals)
    double inc = tsum;
#pragma unroll
    for (int off = 1; off < 64; off <<= 1) {
        double n = __shfl_up(inc, off, 64);
        if (lane >= off) inc += n;
    }
    if (lane == 63) ws[wid] = inc;
    __syncthreads();
    const double btot = ws[0] + ws[1] + ws[2] + ws[3];

    // ---- publish + lookback (thread 0)
    if (threadIdx.x == 0) {
        if (chunk == 0) {
            *(volatile double*)&incl[vid] = btot;
            __threadfence();
            __hip_atomic_store(&flag[vid], 2, __ATOMIC_RELEASE, __HIP_MEMORY_SCOPE_AGENT);
            s_excl = 0.0;
        } else {
            *(volatile double*)&agg[vid] = btot;
            __threadfence();
            __hip_atomic_store(&flag[vid], 1, __ATOMIC_RELEASE, __HIP_MEMORY_SCOPE_AGENT);
            double acc = 0.0;
            int p = vid - 1;
            for (;;) {
                int f = __hip_atomic_load(&flag[p], __ATOMIC_ACQUIRE, __HIP_MEMORY_SCOPE_AGENT);
                if (f == 2)      { acc += *(volatile double*)&incl[p]; break; }
                else if (f == 1) { acc += *(volatile double*)&agg[p];  --p;  }
                // f == 0: predecessor took its ticket before us => it is
                // resident and will publish; spin.
            }
            *(volatile double*)&incl[vid] = acc + btot;
            __threadfence();
            __hip_atomic_store(&flag[vid], 2, __ATOMIC_RELEASE, __HIP_MEMORY_SCOPE_AGENT);
            s_excl = acc;
        }
    }
    __syncthreads();

    double run = (double)phase_state[row] + s_excl + (inc - tsum);
#pragma unroll
    for (int w = 0; w < THREADS / 64; ++w)
        if (w < wid) run += ws[w];

    if (chunk == NCHUNK - 1 && threadIdx.x == 0)
        next_state[row] = (float)((double)phase_state[row] + s_excl + btot);

    // ---- load oq
    float o[VPT];
    {
        const float4* ob = (const float4*)(oq + base_idx);
#pragma unroll
        for (int j = 0; j < VPT / 4; ++j) {
            float4 v = ob[j];
            o[4 * j + 0] = v.x; o[4 * j + 1] = v.y;
            o[4 * j + 2] = v.z; o[4 * j + 3] = v.w;
        }
    }

    // ---- accumulate + pulse; one v_cos per element, arg in revolutions
    float outv[VPT];
#pragma unroll
    for (int i = 0; i < VPT; ++i) {
        run += (double)st[i];
        float ph  = (float)(run - floor(run));     // wrapped phase in [0,1)
        float oqv = o[i];
        float tp  = oqv * 0.66f;
        float tn  = oqv - tp;
        bool  is_rise  = ph < tp;
        bool  in_pulse = ph < oqv;
        float num = is_rise ? ph : (ph - tp);
        float den = is_rise ? (tp + 1e-6f) : (2.0f * tn + 1e-6f);
        // cos(pi * num/den) == v_cos(0.5 * num/den revolutions)
        float rev = 0.5f * num * __builtin_amdgcn_rcpf(den);
        float c   = __builtin_amdgcn_cosf(rev);
        outv[i] = is_rise ? 0.5f * (1.0f - c) : (in_pulse ? c : 0.0f);
    }

    float4* wb = (float4*)(wav + base_idx);
#pragma unroll
    for (int j = 0; j < VPT / 4; ++j) {
        wb[j] = make_float4(outv[4 * j + 0], outv[4 * j + 1],
                            outv[4 * j + 2], outv[4 * j + 3]);
    }
}

extern "C" void kernel_launch(void* const* d_in, const int* in_sizes, int n_in,
                              void* d_out, int out_size, void* d_ws, size_t ws_size,
                              hipStream_t stream)
{
    const float* f0          = (const float*)d_in[0];
    const float* oq          = (const float*)d_in[1];
    const float* phase_state = (const float*)d_in[2];
    float* out = (float*)d_out;                 // [B*T] wav, then [B] next_state

    double* agg     = (double*)d_ws;
    double* incl    = agg + NBLK;
    int*    flag    = (int*)(incl + NBLK);
    int*    tickets = flag + NBLK;

    // zero flags + tickets (d_ws is re-poisoned to 0xAA before every launch)
    hipMemsetAsync(flag, 0, (NBLK + BATCH) * sizeof(int), stream);

    dim3 grid(NCHUNK, BATCH);
    k_fused<<<grid, THREADS, 0, stream>>>(f0, oq, phase_state,
                                          agg, incl, flag, tickets,
                                          out, out + (size_t)BATCH * T);
}

// Round 5
// 210.695 us; speedup vs baseline: 7.1577x; 7.1577x over previous
//
#include <hip/hip_runtime.h>
#include <math.h>

// StatefulRosenberg: segmented cumsum (16 rows x 1,048,576) + Rosenberg pulse.
// R3 post-mortem: decoupled lookback regressed 8x (spin-wait serialization,
// VALUBusy 0.9%). R4/R5 = R2 structure + latency fixes in k_emit:
//   - all global loads (f0, oq, chunk-prefix partials) hoisted before the scan
//   - __launch_bounds__(256,8) for 8 blocks/CU residency
//   - non-temporal wav stores (don't evict L3-resident f0/oq)
// R4->R5: __builtin_nontemporal_store needs a native vector type, not
// HIP_vector_type<float,4> -> use ext_vector_type(4) float.
// fp64 phase accumulation kept (np-ref serial f32 cumsum noise ~3e-4 >> ours).

constexpr int BATCH   = 16;
constexpr int T       = 1048576;
constexpr int THREADS = 256;
constexpr int VPT     = 16;               // elements per thread
constexpr int CHUNK   = THREADS * VPT;    // 4096
constexpr int NCHUNK  = T / CHUNK;        // 256

#define INV_SR (1.0f / 48000.0f)

typedef float v4f __attribute__((ext_vector_type(4)));

// ---------------- Pass 1: per-chunk fp64 sums ----------------
__global__ __launch_bounds__(THREADS, 8) void k_chunk_sums(
    const float* __restrict__ f0, double* __restrict__ partial)
{
    const int chunk = blockIdx.x;
    const int row   = blockIdx.y;
    const v4f* base = (const v4f*)(f0 + (size_t)row * T
                     + (size_t)chunk * CHUNK + (size_t)threadIdx.x * VPT);
    v4f v0 = base[0], v1 = base[1], v2 = base[2], v3 = base[3];
    double s = 0.0;
    s += (double)(v0.x * INV_SR) + (double)(v0.y * INV_SR)
       + (double)(v0.z * INV_SR) + (double)(v0.w * INV_SR);
    s += (double)(v1.x * INV_SR) + (double)(v1.y * INV_SR)
       + (double)(v1.z * INV_SR) + (double)(v1.w * INV_SR);
    s += (double)(v2.x * INV_SR) + (double)(v2.y * INV_SR)
       + (double)(v2.z * INV_SR) + (double)(v2.w * INV_SR);
    s += (double)(v3.x * INV_SR) + (double)(v3.y * INV_SR)
       + (double)(v3.z * INV_SR) + (double)(v3.w * INV_SR);
#pragma unroll
    for (int off = 32; off > 0; off >>= 1)
        s += __shfl_down(s, off, 64);
    __shared__ double ws[THREADS / 64];
    const int lane = threadIdx.x & 63, wid = threadIdx.x >> 6;
    if (lane == 0) ws[wid] = s;
    __syncthreads();
    if (threadIdx.x == 0)
        partial[row * NCHUNK + chunk] = ws[0] + ws[1] + ws[2] + ws[3];
}

// ---------------- Pass 2: prefix + intra-chunk scan + Rosenberg pulse ----------------
__global__ __launch_bounds__(THREADS, 8) void k_emit(
    const float* __restrict__ f0, const float* __restrict__ oq,
    const double* __restrict__ partial, const float* __restrict__ phase_state,
    float* __restrict__ wav, float* __restrict__ next_state)
{
    const int chunk = blockIdx.x;
    const int row   = blockIdx.y;
    const int lane  = threadIdx.x & 63, wid = threadIdx.x >> 6;
    const size_t base_idx = (size_t)row * T + (size_t)chunk * CHUNK
                          + (size_t)threadIdx.x * VPT;

    __shared__ double rs[THREADS / 64];   // chunk-prefix partial reduce
    __shared__ double ws[THREADS / 64];   // wave inclusive totals

    // ---- issue ALL global loads up front so they overlap the fp64 scan ----
    const v4f* fb = (const v4f*)(f0 + base_idx);
    const v4f* ob = (const v4f*)(oq + base_idx);
    v4f f_0 = fb[0], f_1 = fb[1], f_2 = fb[2], f_3 = fb[3];
    v4f o_0 = ob[0], o_1 = ob[1], o_2 = ob[2], o_3 = ob[3];
    double pv = (threadIdx.x < chunk) ? partial[row * NCHUNK + threadIdx.x] : 0.0;
    const float pstate = phase_state[row];

    // ---- f32 steps (match ref rounding scale) + thread fp64 sum
    float st[VPT];
    st[ 0]=f_0.x*INV_SR; st[ 1]=f_0.y*INV_SR; st[ 2]=f_0.z*INV_SR; st[ 3]=f_0.w*INV_SR;
    st[ 4]=f_1.x*INV_SR; st[ 5]=f_1.y*INV_SR; st[ 6]=f_1.z*INV_SR; st[ 7]=f_1.w*INV_SR;
    st[ 8]=f_2.x*INV_SR; st[ 9]=f_2.y*INV_SR; st[10]=f_2.z*INV_SR; st[11]=f_2.w*INV_SR;
    st[12]=f_3.x*INV_SR; st[13]=f_3.y*INV_SR; st[14]=f_3.z*INV_SR; st[15]=f_3.w*INV_SR;
    double tsum = 0.0;
#pragma unroll
    for (int i = 0; i < VPT; ++i) tsum += (double)st[i];

    // ---- chunk prefix: parallel reduce of partial[row][0..chunk-1] (L2-hot)
#pragma unroll
    for (int off = 32; off > 0; off >>= 1)
        pv += __shfl_down(pv, off, 64);
    if (lane == 0) rs[wid] = pv;

    // ---- block exclusive scan of per-thread sums
    double inc = tsum;
#pragma unroll
    for (int off = 1; off < 64; off <<= 1) {
        double n = __shfl_up(inc, off, 64);
        if (lane >= off) inc += n;
    }
    if (lane == 63) ws[wid] = inc;
    __syncthreads();

    const double chunkpref = rs[0] + rs[1] + rs[2] + rs[3];
    double run = (double)pstate + chunkpref + (inc - tsum);
#pragma unroll
    for (int w = 0; w < THREADS / 64; ++w)
        if (w < wid) run += ws[w];

    // next_state: unwrapped final phase, written by the last chunk's thread 0
    if (chunk == NCHUNK - 1 && threadIdx.x == 0)
        next_state[row] = (float)((double)pstate + chunkpref
                                  + ws[0] + ws[1] + ws[2] + ws[3]);

    float o[VPT];
    o[ 0]=o_0.x; o[ 1]=o_0.y; o[ 2]=o_0.z; o[ 3]=o_0.w;
    o[ 4]=o_1.x; o[ 5]=o_1.y; o[ 6]=o_1.z; o[ 7]=o_1.w;
    o[ 8]=o_2.x; o[ 9]=o_2.y; o[10]=o_2.z; o[11]=o_2.w;
    o[12]=o_3.x; o[13]=o_3.y; o[14]=o_3.z; o[15]=o_3.w;

    // ---- accumulate + pulse; one v_cos per element, arg in revolutions
    float outv[VPT];
#pragma unroll
    for (int i = 0; i < VPT; ++i) {
        run += (double)st[i];
        float ph  = (float)(run - floor(run));     // wrapped phase in [0,1)
        float oqv = o[i];
        float tp  = oqv * 0.66f;
        float tn  = oqv - tp;
        bool  is_rise  = ph < tp;
        bool  in_pulse = ph < oqv;
        float num = is_rise ? ph : (ph - tp);
        float den = is_rise ? (tp + 1e-6f) : (2.0f * tn + 1e-6f);
        // cos(pi * num/den) == v_cos(0.5 * num/den revolutions)
        float rev = 0.5f * num * __builtin_amdgcn_rcpf(den);
        float c   = __builtin_amdgcn_cosf(rev);
        outv[i] = is_rise ? 0.5f * (1.0f - c) : (in_pulse ? c : 0.0f);
    }

    v4f* wb = (v4f*)(wav + base_idx);
#pragma unroll
    for (int j = 0; j < VPT / 4; ++j) {
        v4f vv;
        vv.x = outv[4 * j + 0]; vv.y = outv[4 * j + 1];
        vv.z = outv[4 * j + 2]; vv.w = outv[4 * j + 3];
        __builtin_nontemporal_store(vv, &wb[j]);
    }
}

extern "C" void kernel_launch(void* const* d_in, const int* in_sizes, int n_in,
                              void* d_out, int out_size, void* d_ws, size_t ws_size,
                              hipStream_t stream)
{
    const float* f0          = (const float*)d_in[0];
    const float* oq          = (const float*)d_in[1];
    const float* phase_state = (const float*)d_in[2];
    float* out = (float*)d_out;                 // [B*T] wav, then [B] next_state

    double* partial = (double*)d_ws;            // B*NCHUNK doubles (32 KB)

    dim3 grid(NCHUNK, BATCH);
    k_chunk_sums<<<grid, THREADS, 0, stream>>>(f0, partial);
    k_emit<<<grid, THREADS, 0, stream>>>(f0, oq, partial, phase_state,
                                         out, out + (size_t)BATCH * T);
}

// Round 6
// 193.094 us; speedup vs baseline: 7.8101x; 1.0912x over previous
//
#include <hip/hip_runtime.h>
#include <math.h>

// StatefulRosenberg: segmented cumsum (16 rows x 1,048,576) + Rosenberg pulse.
// R5 post-mortem: __builtin_nontemporal_store on gfx950 caused 2.4x write
// amplification (WRITE 70->154 MB, partial-line HBM writes + RMW fetches).
// R6 = R5 minus NT stores (plain dwordx4 stores). Keeps:
//   - all global loads (f0, oq, chunk-prefix partials) hoisted before the scan
//   - __launch_bounds__(256,8) for 8 blocks/CU residency
// fp64 phase accumulation kept (np-ref serial f32 cumsum noise ~3e-4 >> ours).

constexpr int BATCH   = 16;
constexpr int T       = 1048576;
constexpr int THREADS = 256;
constexpr int VPT     = 16;               // elements per thread
constexpr int CHUNK   = THREADS * VPT;    // 4096
constexpr int NCHUNK  = T / CHUNK;        // 256

#define INV_SR (1.0f / 48000.0f)

typedef float v4f __attribute__((ext_vector_type(4)));

// ---------------- Pass 1: per-chunk fp64 sums ----------------
__global__ __launch_bounds__(THREADS, 8) void k_chunk_sums(
    const float* __restrict__ f0, double* __restrict__ partial)
{
    const int chunk = blockIdx.x;
    const int row   = blockIdx.y;
    const v4f* base = (const v4f*)(f0 + (size_t)row * T
                     + (size_t)chunk * CHUNK + (size_t)threadIdx.x * VPT);
    v4f v0 = base[0], v1 = base[1], v2 = base[2], v3 = base[3];
    double s = 0.0;
    s += (double)(v0.x * INV_SR) + (double)(v0.y * INV_SR)
       + (double)(v0.z * INV_SR) + (double)(v0.w * INV_SR);
    s += (double)(v1.x * INV_SR) + (double)(v1.y * INV_SR)
       + (double)(v1.z * INV_SR) + (double)(v1.w * INV_SR);
    s += (double)(v2.x * INV_SR) + (double)(v2.y * INV_SR)
       + (double)(v2.z * INV_SR) + (double)(v2.w * INV_SR);
    s += (double)(v3.x * INV_SR) + (double)(v3.y * INV_SR)
       + (double)(v3.z * INV_SR) + (double)(v3.w * INV_SR);
#pragma unroll
    for (int off = 32; off > 0; off >>= 1)
        s += __shfl_down(s, off, 64);
    __shared__ double ws[THREADS / 64];
    const int lane = threadIdx.x & 63, wid = threadIdx.x >> 6;
    if (lane == 0) ws[wid] = s;
    __syncthreads();
    if (threadIdx.x == 0)
        partial[row * NCHUNK + chunk] = ws[0] + ws[1] + ws[2] + ws[3];
}

// ---------------- Pass 2: prefix + intra-chunk scan + Rosenberg pulse ----------------
__global__ __launch_bounds__(THREADS, 8) void k_emit(
    const float* __restrict__ f0, const float* __restrict__ oq,
    const double* __restrict__ partial, const float* __restrict__ phase_state,
    float* __restrict__ wav, float* __restrict__ next_state)
{
    const int chunk = blockIdx.x;
    const int row   = blockIdx.y;
    const int lane  = threadIdx.x & 63, wid = threadIdx.x >> 6;
    const size_t base_idx = (size_t)row * T + (size_t)chunk * CHUNK
                          + (size_t)threadIdx.x * VPT;

    __shared__ double rs[THREADS / 64];   // chunk-prefix partial reduce
    __shared__ double ws[THREADS / 64];   // wave inclusive totals

    // ---- issue ALL global loads up front so they overlap the fp64 scan ----
    const v4f* fb = (const v4f*)(f0 + base_idx);
    const v4f* ob = (const v4f*)(oq + base_idx);
    v4f f_0 = fb[0], f_1 = fb[1], f_2 = fb[2], f_3 = fb[3];
    v4f o_0 = ob[0], o_1 = ob[1], o_2 = ob[2], o_3 = ob[3];
    double pv = (threadIdx.x < chunk) ? partial[row * NCHUNK + threadIdx.x] : 0.0;
    const float pstate = phase_state[row];

    // ---- f32 steps (match ref rounding scale) + thread fp64 sum
    float st[VPT];
    st[ 0]=f_0.x*INV_SR; st[ 1]=f_0.y*INV_SR; st[ 2]=f_0.z*INV_SR; st[ 3]=f_0.w*INV_SR;
    st[ 4]=f_1.x*INV_SR; st[ 5]=f_1.y*INV_SR; st[ 6]=f_1.z*INV_SR; st[ 7]=f_1.w*INV_SR;
    st[ 8]=f_2.x*INV_SR; st[ 9]=f_2.y*INV_SR; st[10]=f_2.z*INV_SR; st[11]=f_2.w*INV_SR;
    st[12]=f_3.x*INV_SR; st[13]=f_3.y*INV_SR; st[14]=f_3.z*INV_SR; st[15]=f_3.w*INV_SR;
    double tsum = 0.0;
#pragma unroll
    for (int i = 0; i < VPT; ++i) tsum += (double)st[i];

    // ---- chunk prefix: parallel reduce of partial[row][0..chunk-1] (L2-hot)
#pragma unroll
    for (int off = 32; off > 0; off >>= 1)
        pv += __shfl_down(pv, off, 64);
    if (lane == 0) rs[wid] = pv;

    // ---- block exclusive scan of per-thread sums
    double inc = tsum;
#pragma unroll
    for (int off = 1; off < 64; off <<= 1) {
        double n = __shfl_up(inc, off, 64);
        if (lane >= off) inc += n;
    }
    if (lane == 63) ws[wid] = inc;
    __syncthreads();

    const double chunkpref = rs[0] + rs[1] + rs[2] + rs[3];
    double run = (double)pstate + chunkpref + (inc - tsum);
#pragma unroll
    for (int w = 0; w < THREADS / 64; ++w)
        if (w < wid) run += ws[w];

    // next_state: unwrapped final phase, written by the last chunk's thread 0
    if (chunk == NCHUNK - 1 && threadIdx.x == 0)
        next_state[row] = (float)((double)pstate + chunkpref
                                  + ws[0] + ws[1] + ws[2] + ws[3]);

    float o[VPT];
    o[ 0]=o_0.x; o[ 1]=o_0.y; o[ 2]=o_0.z; o[ 3]=o_0.w;
    o[ 4]=o_1.x; o[ 5]=o_1.y; o[ 6]=o_1.z; o[ 7]=o_1.w;
    o[ 8]=o_2.x; o[ 9]=o_2.y; o[10]=o_2.z; o[11]=o_2.w;
    o[12]=o_3.x; o[13]=o_3.y; o[14]=o_3.z; o[15]=o_3.w;

    // ---- accumulate + pulse; one v_cos per element, arg in revolutions
    float outv[VPT];
#pragma unroll
    for (int i = 0; i < VPT; ++i) {
        run += (double)st[i];
        float ph  = (float)(run - floor(run));     // wrapped phase in [0,1)
        float oqv = o[i];
        float tp  = oqv * 0.66f;
        float tn  = oqv - tp;
        bool  is_rise  = ph < tp;
        bool  in_pulse = ph < oqv;
        float num = is_rise ? ph : (ph - tp);
        float den = is_rise ? (tp + 1e-6f) : (2.0f * tn + 1e-6f);
        // cos(pi * num/den) == v_cos(0.5 * num/den revolutions)
        float rev = 0.5f * num * __builtin_amdgcn_rcpf(den);
        float c   = __builtin_amdgcn_cosf(rev);
        outv[i] = is_rise ? 0.5f * (1.0f - c) : (in_pulse ? c : 0.0f);
    }

    v4f* wb = (v4f*)(wav + base_idx);
#pragma unroll
    for (int j = 0; j < VPT / 4; ++j) {
        v4f vv;
        vv.x = outv[4 * j + 0]; vv.y = outv[4 * j + 1];
        vv.z = outv[4 * j + 2]; vv.w = outv[4 * j + 3];
        wb[j] = vv;
    }
}

extern "C" void kernel_launch(void* const* d_in, const int* in_sizes, int n_in,
                              void* d_out, int out_size, void* d_ws, size_t ws_size,
                              hipStream_t stream)
{
    const float* f0          = (const float*)d_in[0];
    const float* oq          = (const float*)d_in[1];
    const float* phase_state = (const float*)d_in[2];
    float* out = (float*)d_out;                 // [B*T] wav, then [B] next_state

    double* partial = (double*)d_ws;            // B*NCHUNK doubles (32 KB)

    dim3 grid(NCHUNK, BATCH);
    k_chunk_sums<<<grid, THREADS, 0, stream>>>(f0, partial);
    k_emit<<<grid, THREADS, 0, stream>>>(f0, oq, partial, phase_state,
                                         out, out + (size_t)BATCH * T);
}

// Round 7
// 178.852 us; speedup vs baseline: 8.4321x; 1.0796x over previous
//
#include <hip/hip_runtime.h>
#include <math.h>

// StatefulRosenberg: segmented cumsum (16 rows x 1,048,576) + Rosenberg pulse.
// R6 post-mortem: hoisting oq above the scan caused scratch spills
// (+24 MB FETCH / +45 MB WRITE = ~11 dwords x 1M threads). R7:
//   - oq loaded AFTER the scan barrier (R2 placement) -> no spill
//   - per-element phase accumulation moved f64 -> f32: wrap the f64 thread
//     base once, then 16 f32 adds + v_fract (max unwrapped 1.0003, exact)
//   - f0/partial/pstate still hoisted pre-scan; __launch_bounds__(256,8)
// fp64 kept for all scan infrastructure (np-ref serial f32 cumsum noise
// ~3e-4 >> our error).

constexpr int BATCH   = 16;
constexpr int T       = 1048576;
constexpr int THREADS = 256;
constexpr int VPT     = 16;               // elements per thread
constexpr int CHUNK   = THREADS * VPT;    // 4096
constexpr int NCHUNK  = T / CHUNK;        // 256

#define INV_SR (1.0f / 48000.0f)

typedef float v4f __attribute__((ext_vector_type(4)));

// ---------------- Pass 1: per-chunk fp64 sums ----------------
__global__ __launch_bounds__(THREADS, 8) void k_chunk_sums(
    const float* __restrict__ f0, double* __restrict__ partial)
{
    const int chunk = blockIdx.x;
    const int row   = blockIdx.y;
    const v4f* base = (const v4f*)(f0 + (size_t)row * T
                     + (size_t)chunk * CHUNK + (size_t)threadIdx.x * VPT);
    v4f v0 = base[0], v1 = base[1], v2 = base[2], v3 = base[3];
    double s = 0.0;
    s += (double)(v0.x * INV_SR) + (double)(v0.y * INV_SR)
       + (double)(v0.z * INV_SR) + (double)(v0.w * INV_SR);
    s += (double)(v1.x * INV_SR) + (double)(v1.y * INV_SR)
       + (double)(v1.z * INV_SR) + (double)(v1.w * INV_SR);
    s += (double)(v2.x * INV_SR) + (double)(v2.y * INV_SR)
       + (double)(v2.z * INV_SR) + (double)(v2.w * INV_SR);
    s += (double)(v3.x * INV_SR) + (double)(v3.y * INV_SR)
       + (double)(v3.z * INV_SR) + (double)(v3.w * INV_SR);
#pragma unroll
    for (int off = 32; off > 0; off >>= 1)
        s += __shfl_down(s, off, 64);
    __shared__ double ws[THREADS / 64];
    const int lane = threadIdx.x & 63, wid = threadIdx.x >> 6;
    if (lane == 0) ws[wid] = s;
    __syncthreads();
    if (threadIdx.x == 0)
        partial[row * NCHUNK + chunk] = ws[0] + ws[1] + ws[2] + ws[3];
}

// ---------------- Pass 2: prefix + intra-chunk scan + Rosenberg pulse ----------------
__global__ __launch_bounds__(THREADS, 8) void k_emit(
    const float* __restrict__ f0, const float* __restrict__ oq,
    const double* __restrict__ partial, const float* __restrict__ phase_state,
    float* __restrict__ wav, float* __restrict__ next_state)
{
    const int chunk = blockIdx.x;
    const int row   = blockIdx.y;
    const int lane  = threadIdx.x & 63, wid = threadIdx.x >> 6;
    const size_t base_idx = (size_t)row * T + (size_t)chunk * CHUNK
                          + (size_t)threadIdx.x * VPT;

    __shared__ double rs[THREADS / 64];   // chunk-prefix partial reduce
    __shared__ double ws[THREADS / 64];   // wave inclusive totals

    // ---- pre-scan loads (needed before the scan anyway) ----
    const v4f* fb = (const v4f*)(f0 + base_idx);
    v4f f_0 = fb[0], f_1 = fb[1], f_2 = fb[2], f_3 = fb[3];
    double pv = (threadIdx.x < chunk) ? partial[row * NCHUNK + threadIdx.x] : 0.0;
    const float pstate = phase_state[row];

    // ---- f32 steps (match ref rounding scale) + thread fp64 sum
    float st[VPT];
    st[ 0]=f_0.x*INV_SR; st[ 1]=f_0.y*INV_SR; st[ 2]=f_0.z*INV_SR; st[ 3]=f_0.w*INV_SR;
    st[ 4]=f_1.x*INV_SR; st[ 5]=f_1.y*INV_SR; st[ 6]=f_1.z*INV_SR; st[ 7]=f_1.w*INV_SR;
    st[ 8]=f_2.x*INV_SR; st[ 9]=f_2.y*INV_SR; st[10]=f_2.z*INV_SR; st[11]=f_2.w*INV_SR;
    st[12]=f_3.x*INV_SR; st[13]=f_3.y*INV_SR; st[14]=f_3.z*INV_SR; st[15]=f_3.w*INV_SR;
    double tsum = 0.0;
#pragma unroll
    for (int i = 0; i < VPT; ++i) tsum += (double)st[i];

    // ---- chunk prefix: parallel reduce of partial[row][0..chunk-1] (L2-hot)
#pragma unroll
    for (int off = 32; off > 0; off >>= 1)
        pv += __shfl_down(pv, off, 64);
    if (lane == 0) rs[wid] = pv;

    // ---- block exclusive scan of per-thread sums
    double inc = tsum;
#pragma unroll
    for (int off = 1; off < 64; off <<= 1) {
        double n = __shfl_up(inc, off, 64);
        if (lane >= off) inc += n;
    }
    if (lane == 63) ws[wid] = inc;
    __syncthreads();

    const double chunkpref = rs[0] + rs[1] + rs[2] + rs[3];
    double run = (double)pstate + chunkpref + (inc - tsum);
#pragma unroll
    for (int w = 0; w < THREADS / 64; ++w)
        if (w < wid) run += ws[w];

    // next_state: unwrapped final phase, written by the last chunk's thread 0
    if (chunk == NCHUNK - 1 && threadIdx.x == 0)
        next_state[row] = (float)((double)pstate + chunkpref
                                  + ws[0] + ws[1] + ws[2] + ws[3]);

    // wrap the thread base ONCE in f64; per-element accumulation is f32.
    // max unwrapped value < 1 + 16*(1/48000) -> single fract suffices.
    float runf = (float)(run - floor(run));

    // ---- oq load AFTER the scan (pre-scan hoist caused scratch spills, R6)
    const v4f* ob = (const v4f*)(oq + base_idx);
    v4f o_0 = ob[0], o_1 = ob[1], o_2 = ob[2], o_3 = ob[3];
    float o[VPT];
    o[ 0]=o_0.x; o[ 1]=o_0.y; o[ 2]=o_0.z; o[ 3]=o_0.w;
    o[ 4]=o_1.x; o[ 5]=o_1.y; o[ 6]=o_1.z; o[ 7]=o_1.w;
    o[ 8]=o_2.x; o[ 9]=o_2.y; o[10]=o_2.z; o[11]=o_2.w;
    o[12]=o_3.x; o[13]=o_3.y; o[14]=o_3.z; o[15]=o_3.w;

    // ---- accumulate + pulse; one v_cos per element, arg in revolutions
    float outv[VPT];
#pragma unroll
    for (int i = 0; i < VPT; ++i) {
        runf += st[i];
        float ph  = __builtin_amdgcn_fractf(runf);   // wrapped phase in [0,1)
        float oqv = o[i];
        float tp  = oqv * 0.66f;
        bool  is_rise  = ph < tp;
        bool  in_pulse = ph < oqv;
        float num = is_rise ? ph : (ph - tp);
        float den = is_rise ? fmaf(oqv, 0.66f, 1e-6f)    // tp + eps
                            : fmaf(oqv, 0.68f, 1e-6f);   // 2*tn + eps
        // cos(pi * num/den) == v_cos(0.5 * num/den revolutions)
        float rev = 0.5f * num * __builtin_amdgcn_rcpf(den);
        float c   = __builtin_amdgcn_cosf(rev);
        outv[i] = is_rise ? 0.5f * (1.0f - c) : (in_pulse ? c : 0.0f);
    }

    v4f* wb = (v4f*)(wav + base_idx);
#pragma unroll
    for (int j = 0; j < VPT / 4; ++j) {
        v4f vv;
        vv.x = outv[4 * j + 0]; vv.y = outv[4 * j + 1];
        vv.z = outv[4 * j + 2]; vv.w = outv[4 * j + 3];
        wb[j] = vv;
    }
}

extern "C" void kernel_launch(void* const* d_in, const int* in_sizes, int n_in,
                              void* d_out, int out_size, void* d_ws, size_t ws_size,
                              hipStream_t stream)
{
    const float* f0          = (const float*)d_in[0];
    const float* oq          = (const float*)d_in[1];
    const float* phase_state = (const float*)d_in[2];
    float* out = (float*)d_out;                 // [B*T] wav, then [B] next_state

    double* partial = (double*)d_ws;            // B*NCHUNK doubles (32 KB)

    dim3 grid(NCHUNK, BATCH);
    k_chunk_sums<<<grid, THREADS, 0, stream>>>(f0, partial);
    k_emit<<<grid, THREADS, 0, stream>>>(f0, oq, partial, phase_state,
                                         out, out + (size_t)BATCH * T);
}